// Round 13
// baseline (1063.958 us; speedup 1.0000x reference)
//
#include <hip/hip_runtime.h>

typedef short short8 __attribute__((ext_vector_type(8)));
typedef float floatx4 __attribute__((ext_vector_type(4)));

#define ROWS 81
#define CDIM 256
#define NTHR 1024
// LDS layout (153600 B -> 1 block/CU)
#define RAW  0          // f32 [81][256] linear gr-major (DMA target), 82944 B
#define XT   82944      // bf16 [81][256] p-major rows r=p*9+m, swizzle SWX, stride 512B
#define QT   124416     // bf16 [96][128] padded, swizzle (r&15)<<4, stride 256B (24576)
#define SC   148992     // 4 partial gram tiles [16][16] f32 (4096)
#define AB   153088     // attn f32 [9][12] (432, padded)
#define TOT  153600

#define SWX(r) ((((r) & 15) << 4) ^ (((r) & 8) << 3))

// raw barrier: waits LDS ops only — global_load_lds (vmcnt) stays in flight
#define BAR_LGKM() asm volatile("s_waitcnt lgkmcnt(0)\n\ts_barrier" ::: "memory")

#define GLOAD16(g, l) __builtin_amdgcn_global_load_lds( \
    (const __attribute__((address_space(1))) unsigned int*)(g), \
    (__attribute__((address_space(3))) unsigned int*)(l), 16, 0, 0)

__device__ __forceinline__ unsigned short f2bf(float f) {
    union { float f; unsigned int u; } v; v.f = f;
    return (unsigned short)((v.u + 0x7FFFu + ((v.u >> 16) & 1u)) >> 16);
}

__device__ __forceinline__ unsigned int cvtpk(float lo, float hi) {
    unsigned int r;
    asm("v_cvt_pk_bf16_f32 %0, %1, %2" : "=v"(r) : "v"(lo), "v"(hi));
    return r;
}

__device__ __forceinline__ float bflo(unsigned int u) { return __uint_as_float(u << 16); }
__device__ __forceinline__ float bfhi(unsigned int u) { return __uint_as_float(u & 0xffff0000u); }

__global__ void wconv_kernel(const float* __restrict__ W,
                             unsigned short* __restrict__ Wb, int n) {
    int i = blockIdx.x * 256 + threadIdx.x;
    if (i < n) Wb[i] = f2bf(W[i]);
}

__global__ void __launch_bounds__(NTHR, 4)
attn_kernel(const float* __restrict__ x,
            const unsigned short* __restrict__ Wb,
            const float* __restrict__ b_fc,
            const int* __restrict__ block_idx,
            const int* __restrict__ match_vec,
            float* __restrict__ out,
            int B, int nIter)
{
    __shared__ __align__(16) char smem[TOT];
    const int t     = threadIdx.x;
    const int lane  = t & 63;
    const int wave  = t >> 6;       // 0..15
    const int l15   = lane & 15;
    const int kg    = lane >> 4;    // 0..3
    const int base  = blockIdx.x * nIter;
    if (base >= B) return;

    // ---- proj tiling: wave -> (rg 0..3: 24 rows) x (hg 0..3: 32 h-cols) ----
    const int rg = wave >> 2;
    const int hg = wave & 3;

    // W^T B-fragments (L2-hot), 32 VGPR
    short8 wfrag[2][8];
#pragma unroll
    for (int s2 = 0; s2 < 2; ++s2) {
        const unsigned short* wr = Wb + (hg * 32 + s2 * 16 + l15) * CDIM + kg * 8;
#pragma unroll
        for (int ks = 0; ks < 8; ++ks)
            wfrag[s2][ks] = *(const short8*)(wr + ks * 32);
    }
    float bias2[2];
    bias2[0] = b_fc[hg * 32 + l15];
    bias2[1] = b_fc[hg * 32 + 16 + l15];

    // ---- per-thread static offsets ----
    // convert/DMA 16B units: u = t + 1024j  (5184 units)
    int rawoff[6], xtoff[6];
#pragma unroll
    for (int j = 0; j < 6; ++j) {
        int u = t + 1024 * j;
        rawoff[j] = RAW + u * 16;
        int gr = u >> 6;                   // source row
        int c0 = (u & 63) * 4;             // f32 col
        int hh = gr / 9, ww = gr - hh * 9;
        int p  = (hh % 3) * 3 + (ww % 3);
        int m  = (hh / 3) * 3 + (ww / 3);
        int r  = p * 9 + m;
        xtoff[j] = XT + r * 512 + ((c0 * 2) ^ SWX(r));
    }
    // epilogue ownership: thread t<576 owns quad (p_, c_)
    const int p_ = (t < 576) ? (t >> 6) : 0;
    const int c_ = (lane) * 4;             // f32 col within pixel (0..252)
    int groff[9];                          // f32 index of (row gr(k,p_), col c_)
#pragma unroll
    for (int k = 0; k < 9; ++k) {
        int hh = (k / 3) * 3 + p_ / 3;
        int ww = (k % 3) * 3 + p_ % 3;
        groff[k] = (hh * 9 + ww) * CDIM + c_;
    }

    // ---- prologue: DMA batch[base] -> RAW ----
    {
        const float* xb = x + (size_t)base * (ROWS * CDIM);
#pragma unroll
        for (int j = 0; j < 6; ++j)
            if (j < 5 || t < 64) GLOAD16(xb + (t + 1024 * j) * 4, smem + rawoff[j]);
    }

    for (int it = 0; it < nIter && base + it < B; ++it) {
        const int b = base + it;
        const bool hasNext = (it + 1 < nIter) && (b + 1 < B);

        int cm = 0;
        if (t < 9) cm = match_vec[block_idx[b]];

        __syncthreads();   // TOP: drains vmcnt -> RAW(b) complete

        // ---- convert RAW f32 -> XT bf16 (permute + swizzle), conflict-free ----
#pragma unroll
        for (int j = 0; j < 6; ++j) {
            if (j < 5 || t < 64) {
                float4 a = *(const float4*)(smem + rawoff[j]);
                uint2 w;
                w.x = cvtpk(a.x, a.y);
                w.y = cvtpk(a.z, a.w);
                *(uint2*)(smem + xtoff[j]) = w;
            }
        }
        // ---- load v(b) into registers (bf16-packed), 18 VGPR ----
        unsigned v0[9], v1[9];
        if (t < 576) {
#pragma unroll
            for (int m = 0; m < 9; ++m) {
                float4 q = *(const float4*)(smem + RAW + groff[m] * 4);
                v0[m] = cvtpk(q.x, q.y);
                v1[m] = cvtpk(q.z, q.w);
            }
        }
        __syncthreads();   // B1: XT ready, RAW free

        // ---- issue DMA(b+1) -> RAW (stays in flight across raw barriers) ----
        if (hasNext) {
            const float* xn = x + (size_t)(b + 1) * (ROWS * CDIM);
#pragma unroll
            for (int j = 0; j < 6; ++j)
                if (j < 5 || t < 64) GLOAD16(xn + (t + 1024 * j) * 4, smem + rawoff[j]);
        }

        // ---- proj: q[<=96 x 128] = x @ W^T ----
        {
            floatx4 acc[2][2];
#pragma unroll
            for (int ti = 0; ti < 2; ++ti)
#pragma unroll
                for (int s2 = 0; s2 < 2; ++s2)
#pragma unroll
                    for (int j = 0; j < 4; ++j) acc[ti][s2][j] = 0.f;
#pragma unroll
            for (int ks = 0; ks < 8; ++ks) {
                int cb = ks * 64 + kg * 16;
                {   // tile A: rows rg*24 + l15
                    int r = rg * 24 + l15;
                    short8 a = *(const short8*)(smem + XT + r * 512 + (cb ^ SWX(r)));
                    acc[0][0] = __builtin_amdgcn_mfma_f32_16x16x32_bf16(a, wfrag[0][ks], acc[0][0], 0, 0, 0);
                    acc[0][1] = __builtin_amdgcn_mfma_f32_16x16x32_bf16(a, wfrag[1][ks], acc[0][1], 0, 0, 0);
                }
                if (rg < 3) {   // tile B: rows rg*24+16+l15 (rg==3 would be all-pad)
                    int r = rg * 24 + 16 + l15;
                    short8 a = *(const short8*)(smem + XT + r * 512 + (cb ^ SWX(r)));
                    acc[1][0] = __builtin_amdgcn_mfma_f32_16x16x32_bf16(a, wfrag[0][ks], acc[1][0], 0, 0, 0);
                    acc[1][1] = __builtin_amdgcn_mfma_f32_16x16x32_bf16(a, wfrag[1][ks], acc[1][1], 0, 0, 0);
                }
            }
#pragma unroll
            for (int ti = 0; ti < 2; ++ti) {
                if (ti == 1 && rg == 3) continue;
#pragma unroll
                for (int s2 = 0; s2 < 2; ++s2) {
                    int h2 = (hg * 32 + s2 * 16 + l15) * 2;
#pragma unroll
                    for (int reg = 0; reg < 4; ++reg) {
                        int r = rg * 24 + ti * 16 + kg * 4 + reg;   // <= 87 < 96
                        *(unsigned short*)(smem + QT + r * 256 + (h2 ^ ((r & 15) << 4))) =
                            f2bf(acc[ti][s2][reg] + bias2[s2]);
                    }
                }
            }
        }
        BAR_LGKM();   // B2: q ready (DMA still in flight)

        // ---- gram partials: waves 0..3, 9 k-chunks each ----
        if (wave < 4) {
            floatx4 g;
#pragma unroll
            for (int ii = 0; ii < 4; ++ii) g[ii] = 0.f;
            int nc = (l15 < 9) ? l15 : 8;
#pragma unroll
            for (int s = 0; s < 9; ++s) {
                int ks = wave + s * 4;
                int kk = ks * 32 + kg * 8;
                int p  = kk >> 7;
                int h0 = (kk & 127) * 2;
                int row = p * 9 + nc;
                short8 f = *(const short8*)(smem + QT + row * 256 + (h0 ^ ((row & 15) << 4)));
                g = __builtin_amdgcn_mfma_f32_16x16x32_bf16(f, f, g, 0, 0, 0);
            }
            float* sc = (float*)(smem + SC + wave * 1024);
#pragma unroll
            for (int reg = 0; reg < 4; ++reg)
                sc[(kg * 4 + reg) * 16 + l15] = g[reg];
        }
        BAR_LGKM();   // B3: partials ready

        // ---- masked softmax rows 0..8 -> attn f32 [9][12] ----
        if (t < 9) {
            const float scale = 0.029462782549439483f;   // (128*9)^-0.5
            const float* sc0 = (const float*)(smem + SC);
            const float* sc1 = (const float*)(smem + SC + 1024);
            const float* sc2 = (const float*)(smem + SC + 2048);
            const float* sc3 = (const float*)(smem + SC + 3072);
            float s[9];
            float mx = -1e30f;
#pragma unroll
            for (int m = 0; m < 9; ++m) {
                int o = t * 16 + m;
                float v = (sc0[o] + sc1[o] + sc2[o] + sc3[o]) * scale;
                if (m == t && cm != 1) v -= 100.f;
                s[m] = v;
                mx = fmaxf(mx, v);
            }
            float sum = 0.f;
#pragma unroll
            for (int m = 0; m < 9; ++m) { s[m] = __expf(s[m] - mx); sum += s[m]; }
            float inv = 1.f / sum;
            float* ab = (float*)(smem + AB) + t * 12;
#pragma unroll
            for (int m = 0; m < 9; ++m) ab[m] = s[m] * inv;
        }
        BAR_LGKM();   // B4: attn ready

        // ---- epilogue: out[n][quad] = sum_m attn[n][m] * v[m][quad] ----
        if (t < 576) {
            float* ob = out + (size_t)b * (ROWS * CDIM);
#pragma unroll
            for (int n = 0; n < 9; ++n) {
                const float* abr = (const float*)(smem + AB) + n * 12;
                float4 a03 = *(const float4*)(abr);
                float4 a47 = *(const float4*)(abr + 4);
                float  a8  = abr[8];
                float o0 = 0.f, o1 = 0.f, o2 = 0.f, o3 = 0.f;
#pragma unroll
                for (int m = 0; m < 9; ++m) {
                    float am = (m < 4) ? ((m == 0) ? a03.x : (m == 1) ? a03.y : (m == 2) ? a03.z : a03.w)
                             : (m < 8) ? ((m == 4) ? a47.x : (m == 5) ? a47.y : (m == 6) ? a47.z : a47.w)
                             : a8;
                    o0 += am * bflo(v0[m]);
                    o1 += am * bfhi(v0[m]);
                    o2 += am * bflo(v1[m]);
                    o3 += am * bfhi(v1[m]);
                }
                *(float4*)(ob + groff[n]) = make_float4(o0, o1, o2, o3);
            }
        }
        // loop-top __syncthreads drains the DMA and protects RAW/XT reuse
    }
}

extern "C" void kernel_launch(void* const* d_in, const int* in_sizes, int n_in,
                              void* d_out, int out_size, void* d_ws, size_t ws_size,
                              hipStream_t stream) {
    const float* x    = (const float*)d_in[0];
    const float* W    = (const float*)d_in[1];
    const float* bfc  = (const float*)d_in[2];
    const int*   bidx = (const int*)d_in[3];
    const int*   mvec = (const int*)d_in[4];
    float* outp = (float*)d_out;
    unsigned short* Wb = (unsigned short*)d_ws;

    int nW = in_sizes[1];                       // 128*256
    wconv_kernel<<<(nW + 255) / 256, 256, 0, stream>>>(W, Wb, nW);

    int B = in_sizes[0] / (ROWS * CDIM);        // 8192
    int grid = (B < 256) ? B : 256;
    int nIter = (B + grid - 1) / grid;          // 32
    attn_kernel<<<grid, NTHR, 0, stream>>>(x, Wb, bfc, bidx, mvec, outp, B, nIter);
}